// Round 7
// baseline (391.747 us; speedup 1.0000x reference)
//
#include <hip/hip_runtime.h>
#include <math.h>

#define CIN_    512
#define COUT_   512
#define LATENT_ 512
#define NB_     8
#define HH_     64
#define WW_     64

typedef float f32x16 __attribute__((ext_vector_type(16)));
typedef short bf16x8v __attribute__((ext_vector_type(8)));

// pack two fp32 -> two bf16 (RTNE) in one u32 (low = f0). Verified rounds 5/6.
__device__ inline unsigned pack2bf(float f0, float f1) {
    union { float f; unsigned u; } a0, a1;
    a0.f = f0; a1.f = f1;
    unsigned r0 = a0.u + 0x7fffu + ((a0.u >> 16) & 1u);
    unsigned r1 = a1.u + 0x7fffu + ((a1.u >> 16) & 1u);
    return __builtin_amdgcn_perm(r1, r0, 0x07060302);
}

// ================= single prep kernel: ALL blocks independent =================
// b in [0,32):    demod  (n,quarter) — self-sufficient (computes own s, reads w^2)
// b in [32,320):  wprep  (tap,cb)    — wb[tap][cb][co512][ci16] = bf16(w*RC_W)
// b in [320,2368): xcast (n,cb,hg)   — xt[n][cb][h64][w64][ci16] = bf16(x*s),
//                  s-slice computed in-block from dlat/mw/mb. No halo, no preds.
__global__ __launch_bounds__(256) void prep(
    const float* __restrict__ x, const float* __restrict__ dlat,
    const float* __restrict__ w, const float* __restrict__ mw,
    const float* __restrict__ mb, unsigned short* __restrict__ xt,
    unsigned short* __restrict__ wb, float* __restrict__ dmod)
{
    __shared__ union {
        struct { float rows[8][16 * 67]; float sred[256]; float s16[16]; } xc;
        float wt[16 * 521];
        struct { float dl[512]; float sd[512]; float red[256]; } dm;
    } sm;
    const float RC_W = 0.0147313912747197f;   // 1/sqrt(9*512)
    const float RC_S = 0.0441941738241592f;   // 1/sqrt(512)
    const float RCW2 = 1.0f / 4608.0f;
    int b = blockIdx.x;
    int t = threadIdx.x;

    if (b < 32) {
        // ---- demod: d[n][co] = rsqrt(RCW2 * sum_{tap,ci} s^2 w^2 + 1e-8) ----
        int n = b >> 2;
        int co_base = (b & 3) * 128;
        sm.dm.dl[t]       = dlat[n * LATENT_ + t];
        sm.dm.dl[256 + t] = dlat[n * LATENT_ + 256 + t];
        __syncthreads();
#pragma unroll
        for (int rep = 0; rep < 2; ++rep) {
            int ci = t + rep * 256;
            float acc = 0.f;
            for (int l = 0; l < LATENT_; ++l)
                acc += sm.dm.dl[l] * mw[l * CIN_ + ci];
            float sv = acc * RC_S + mb[ci] + 1.0f;
            sm.dm.sd[ci] = sv * sv;
        }
        __syncthreads();
        int co = co_base + (t & 127);
        int hf = t >> 7;
        float acc = 0.f;
        for (int tap = 0; tap < 9; ++tap)
#pragma unroll 8
            for (int ci = hf * 256; ci < hf * 256 + 256; ++ci) {
                float vw = w[((size_t)tap * 512 + ci) * 512 + co];
                acc += sm.dm.sd[ci] * vw * vw;
            }
        sm.dm.red[t] = acc;
        __syncthreads();
        if (t < 128)
            dmod[n * COUT_ + co_base + t] =
                rsqrtf(RCW2 * (sm.dm.red[t] + sm.dm.red[128 + t]) + 1e-8f);
    } else if (b < 320) {
        // ---- wprep (round-6 verified) ----
        int u   = b - 32;
        int tap = u / 32;
        int cb  = u % 32;
        for (int idx = t; idx < 16 * 512; idx += 256) {
            int ci = idx >> 9;
            int co = idx & 511;
            sm.wt[ci * 521 + co] = w[((size_t)tap * 512 + cb * 16 + ci) * 512 + co];
        }
        __syncthreads();
        unsigned short* dst = wb + (size_t)(tap * 32 + cb) * 512 * 16;
#pragma unroll
        for (int r = 0; r < 4; ++r) {
            int j  = t + 256 * r;
            int co = j >> 1;
            int c8 = (j & 1) * 8;
            uint4 o;
            o.x = pack2bf(sm.wt[(c8 + 0) * 521 + co] * RC_W, sm.wt[(c8 + 1) * 521 + co] * RC_W);
            o.y = pack2bf(sm.wt[(c8 + 2) * 521 + co] * RC_W, sm.wt[(c8 + 3) * 521 + co] * RC_W);
            o.z = pack2bf(sm.wt[(c8 + 4) * 521 + co] * RC_W, sm.wt[(c8 + 5) * 521 + co] * RC_W);
            o.w = pack2bf(sm.wt[(c8 + 6) * 521 + co] * RC_W, sm.wt[(c8 + 7) * 521 + co] * RC_W);
            *(uint4*)&dst[co * 16 + c8] = o;
        }
    } else {
        // ---- xcast: 8 rows, no halo, s-slice computed in-block ----
        int u  = b - 320;            // (n*32 + cb)*8 + hg
        int hg = u & 7;
        int cb = (u >> 3) & 31;
        int n  = u >> 8;
        int h0 = hg * 8;

        int ci = t >> 4;
        int q4 = (t & 15) * 4;
        const float* xb = x + ((size_t)(n * CIN_ + cb * 16 + ci)) * (HH_ * WW_) + h0 * WW_ + q4;
        float4 v[8];
#pragma unroll
        for (int r = 0; r < 8; ++r) v[r] = *(const float4*)(xb + r * WW_);

        // s-slice: s[ci16] = dlat . mw[:,ci] * RC_S + mb + 1
        int sci = t & 15, part = t >> 4;
        {
            float a = 0.f;
            const float* mwp = mw + (size_t)part * 32 * CIN_ + cb * 16 + sci;
            const float* dlp = dlat + n * LATENT_ + part * 32;
#pragma unroll 8
            for (int l = 0; l < 32; ++l)
                a += dlp[l] * mwp[(size_t)l * CIN_];
            sm.xc.sred[part * 16 + sci] = a;
        }
        __syncthreads();
        if (t < 16) {
            float a2 = 0.f;
#pragma unroll
            for (int p = 0; p < 16; ++p) a2 += sm.xc.sred[p * 16 + t];
            sm.xc.s16[t] = a2 * RC_S + mb[cb * 16 + t] + 1.0f;
        }
        // stash x rows (independent of s16)
#pragma unroll
        for (int r = 0; r < 8; ++r) {
            float* dl = &sm.xc.rows[r][ci * 67 + q4];
            dl[0] = v[r].x; dl[1] = v[r].y; dl[2] = v[r].z; dl[3] = v[r].w;
        }
        __syncthreads();

        unsigned short* dstb = xt + (((size_t)(n * 32 + cb) * HH_ + h0) * WW_) * 16;
#pragma unroll
        for (int k = 0; k < 4; ++k) {
            int j   = t + 256 * k;       // 1024 uint4 jobs: 8 rows x 64 wp x 2 c8
            int r   = j >> 7;
            int rem = j & 127;
            int wp  = rem >> 1;
            int c8  = (rem & 1) * 8;
            float f[8];
#pragma unroll
            for (int i = 0; i < 8; ++i)
                f[i] = sm.xc.rows[r][(c8 + i) * 67 + wp] * sm.xc.s16[c8 + i];
            uint4 o;
            o.x = pack2bf(f[0], f[1]);
            o.y = pack2bf(f[2], f[3]);
            o.z = pack2bf(f[4], f[5]);
            o.w = pack2bf(f[6], f[7]);
            *(uint4*)&dstb[((size_t)r * WW_ + wp) * 16 + c8] = o;
        }
    }
}

// ============ main conv: implicit GEMM on 32x32x16 bf16 MFMA ============
// Identical math to round 3/6; xt is now compact [64][64][16] and staging
// applies boundary predicates per uint4 (halo absorbed here).
__global__ __launch_bounds__(256) void conv_mfma(
    const unsigned short* __restrict__ xt,
    const unsigned short* __restrict__ wb,
    const float* __restrict__ dmod,
    float* __restrict__ out)
{
    __shared__ __align__(16) union {
        struct { unsigned short xs[2880]; unsigned short ws[18432]; } s;  // 42624 B
        float o[64 * 129];
    } sm;

    int b   = blockIdx.x;
    int cot = b & 3;
    int wt_ = (b >> 2) & 3;
    int ht  = (b >> 4) & 7;
    int n   = b >> 7;
    int h0 = ht * 8, w0 = wt_ * 16, co0 = cot * 128;

    int t    = threadIdx.x;
    int wv   = t >> 6, lane = t & 63;
    int mh   = wv >> 1, nh = wv & 1;
    int l5   = lane & 31, half = lane >> 5;

    f32x16 acc[2][2];
#pragma unroll
    for (int ms = 0; ms < 2; ++ms)
#pragma unroll
        for (int ns = 0; ns < 2; ++ns)
#pragma unroll
            for (int i = 0; i < 16; ++i) acc[ms][ns][i] = 0.f;

    for (int cb = 0; cb < 32; ++cb) {
        // stage x tile: 10 rows x 18 wp x 16 ci (360 uint4), boundary-predicated
        const unsigned short* xb = xt + ((size_t)(n * 32 + cb) * (HH_ * WW_)) * 16;
        for (int li = t; li < 360; li += 256) {
            int row = li / 36;
            int off = li - row * 36;
            int wp  = off >> 1;
            int c8  = (off & 1) * 8;
            int gh  = h0 - 1 + row;
            int gw  = w0 - 1 + wp;
            uint4 val = make_uint4(0u, 0u, 0u, 0u);
            if (gh >= 0 && gh < HH_ && gw >= 0 && gw < WW_)
                val = *(const uint4*)&xb[((size_t)gh * WW_ + gw) * 16 + c8];
            *(uint4*)&sm.s.xs[row * 288 + off * 8] = val;
        }
        // stage weights: 9 taps x 128 co x 16 ci (each tap = 256 x 16B)
        const unsigned short* wbb = wb + ((size_t)cb * 512 + co0) * 16;
#pragma unroll
        for (int tap = 0; tap < 9; ++tap) {
            *(uint4*)&sm.s.ws[tap * 2048 + t * 8] =
                *(const uint4*)&wbb[(size_t)tap * 32 * 512 * 16 + t * 8];
        }
        __syncthreads();

#pragma unroll
        for (int tap = 0; tap < 9; ++tap) {
            int kh = tap / 3, kw = tap - 3 * (tap / 3);
            bf16x8v bfr[2], afr[2];
#pragma unroll
            for (int ns = 0; ns < 2; ++ns) {
                int co_l = nh * 64 + ns * 32 + l5;
                bfr[ns] = *(const bf16x8v*)&sm.s.ws[tap * 2048 + co_l * 16 + half * 8];
            }
#pragma unroll
            for (int ms = 0; ms < 2; ++ms) {
                int pr = mh * 4 + ms * 2 + (l5 >> 4);
                int pc = l5 & 15;
                int pos = (pr + kh) * 18 + (pc + kw);
                afr[ms] = *(const bf16x8v*)&sm.s.xs[pos * 16 + half * 8];
            }
#pragma unroll
            for (int ms = 0; ms < 2; ++ms)
#pragma unroll
                for (int ns = 0; ns < 2; ++ns)
                    acc[ms][ns] = __builtin_amdgcn_mfma_f32_32x32x16_bf16(
                        afr[ms], bfr[ns], acc[ms][ns], 0, 0, 0);
        }
        __syncthreads();
    }

    // epilogue: demod + LDS transpose + coalesced float4 stores (2 passes)
    for (int p = 0; p < 2; ++p) {
        __syncthreads();
        int co_l = nh * 64 + p * 32 + l5;
        int bco  = nh * 32 + l5;
        float dv = dmod[n * COUT_ + co0 + co_l];
#pragma unroll
        for (int ms = 0; ms < 2; ++ms) {
#pragma unroll
            for (int reg = 0; reg < 16; ++reg) {
                int ml = (reg & 3) + 8 * (reg >> 2) + 4 * half;
                int pr = mh * 4 + ms * 2 + (ml >> 4);
                int pc = ml & 15;
                sm.o[bco * 129 + pr * 16 + pc] = acc[ms][p][reg] * dv;
            }
        }
        __syncthreads();
        for (int j = t; j < 2048; j += 256) {
            int wq = j & 3;
            int pairidx = j >> 2;
            int row  = pairidx & 7;
            int bco2 = pairidx >> 3;
            int co = (bco2 >> 5) * 64 + p * 32 + (bco2 & 31);
            const float* src = &sm.o[bco2 * 129 + row * 16 + wq * 4];
            float4 v = make_float4(src[0], src[1], src[2], src[3]);
            *(float4*)&out[(((size_t)n * COUT_ + co0 + co) * HH_ + h0 + row) * WW_ + w0 + wq * 4] = v;
        }
    }
}

extern "C" void kernel_launch(void* const* d_in, const int* in_sizes, int n_in,
                              void* d_out, int out_size, void* d_ws, size_t ws_size,
                              hipStream_t stream) {
    const float* x    = (const float*)d_in[0];
    const float* dlat = (const float*)d_in[1];
    const float* w    = (const float*)d_in[2];
    const float* mw   = (const float*)d_in[3];
    const float* mb   = (const float*)d_in[4];
    float* out = (float*)d_out;

    char* ws = (char*)d_ws;
    float* dmod = (float*)(ws);                            // 4096 f
    unsigned short* xt = (unsigned short*)(ws + 16384);    // 8*32*64*64*16 u16 = 33.5 MB
    unsigned short* wb = (unsigned short*)(ws + 16384 + 33554432);  // 4.7 MB

    prep<<<2368, 256, 0, stream>>>(x, dlat, w, mw, mb, xt, wb, dmod);
    conv_mfma<<<1024, 256, 0, stream>>>(xt, wb, dmod, out);
}

// Round 8
// 330.718 us; speedup vs baseline: 1.1845x; 1.1845x over previous
//
#include <hip/hip_runtime.h>
#include <math.h>

#define CIN_    512
#define COUT_   512
#define LATENT_ 512
#define NB_     8
#define HH_     64
#define WW_     64

typedef float f32x16 __attribute__((ext_vector_type(16)));
typedef short bf16x8v __attribute__((ext_vector_type(8)));

__device__ inline unsigned short f2bf(float f) {
    union { float f; unsigned u; } v; v.f = f;
    unsigned r = v.u + 0x7fffu + ((v.u >> 16) & 1u);
    return (unsigned short)(r >> 16);
}

// pack two fp32 -> two bf16 (RTNE) in one u32 (low = f0). Verified rounds 5/6.
__device__ inline unsigned pack2bf(float f0, float f1) {
    union { float f; unsigned u; } a0, a1;
    a0.f = f0; a1.f = f1;
    unsigned r0 = a0.u + 0x7fffu + ((a0.u >> 16) & 1u);
    unsigned r1 = a1.u + 0x7fffu + ((a1.u >> 16) & 1u);
    return __builtin_amdgcn_perm(r1, r0, 0x07060302);
}

// ============ prep1: wsq (b<1024) + wprep (1024..1311) + style (1312..1319)
// (round-3 structure; wprep stores widened to uint4 per round 6 — measured neutral)
__global__ __launch_bounds__(256) void prep1(
    const float* __restrict__ w, const float* __restrict__ dlat,
    const float* __restrict__ mw, const float* __restrict__ mb,
    float* __restrict__ wsq, unsigned short* __restrict__ wb,
    float* __restrict__ s)
{
    __shared__ float smem[16 * 521];
    const float RC_W = 0.0147313912747197f;   // 1/sqrt(9*512)
    const float RC_S = 0.0441941738241592f;   // 1/sqrt(512)
    int b = blockIdx.x;
    int t = threadIdx.x;

    if (b < 1024) {
        // ---- wsq[ci][co] = sum_tap w^2 (fp32, exact demod) ----
        int idx = b * 256 + t;
        float acc = 0.f;
#pragma unroll
        for (int tap = 0; tap < 9; ++tap) {
            float v = w[tap * (CIN_ * COUT_) + idx];
            acc += v * v;
        }
        wsq[idx] = acc;
    } else if (b < 1312) {
        // ---- wprep: wb[tap][cb][co 512][ci16] = w[tap][ci][co]*RC_W (bf16, transposed)
        int bb  = b - 1024;
        int tap = bb / 32;
        int cb  = bb % 32;
        for (int idx = t; idx < 16 * 512; idx += 256) {
            int ci = idx >> 9;
            int co = idx & 511;
            smem[ci * 521 + co] = w[((size_t)tap * 512 + cb * 16 + ci) * 512 + co];
        }
        __syncthreads();
        unsigned short* dst = wb + (size_t)(tap * 32 + cb) * 512 * 16;
#pragma unroll
        for (int r = 0; r < 4; ++r) {
            int j  = t + 256 * r;          // 1024 uint4 jobs
            int co = j >> 1;
            int c8 = (j & 1) * 8;
            uint4 o;
            o.x = pack2bf(smem[(c8 + 0) * 521 + co] * RC_W, smem[(c8 + 1) * 521 + co] * RC_W);
            o.y = pack2bf(smem[(c8 + 2) * 521 + co] * RC_W, smem[(c8 + 3) * 521 + co] * RC_W);
            o.z = pack2bf(smem[(c8 + 4) * 521 + co] * RC_W, smem[(c8 + 5) * 521 + co] * RC_W);
            o.w = pack2bf(smem[(c8 + 6) * 521 + co] * RC_W, smem[(c8 + 7) * 521 + co] * RC_W);
            *(uint4*)&dst[co * 16 + c8] = o;
        }
    } else {
        // ---- style: s[n][ci] = dlat . (mw*RC_S) + mb + 1 ----
        int n = b - 1312;
        for (int i = t; i < LATENT_; i += 256) smem[i] = dlat[n * LATENT_ + i];
        __syncthreads();
        for (int ci = t; ci < CIN_; ci += 256) {
            float acc = 0.f;
            for (int l = 0; l < LATENT_; ++l)
                acc += smem[l] * mw[l * CIN_ + ci];
            s[n * CIN_ + ci] = acc * RC_S + mb[ci] + 1.0f;
        }
    }
}

// ============ prep2: demod (b<8) + xprep (8..16903)  — round-3 exact
// xprep: xt[n][cb][hp 66][wp 66][ci16] bf16 = x*s with zero-padded halo.
// Many tiny fully-parallel blocks — empirically beats serial-row variants.
__global__ __launch_bounds__(256) void prep2(
    const float* __restrict__ x, const float* __restrict__ s,
    const float* __restrict__ wsq, float* __restrict__ dmod,
    unsigned short* __restrict__ xt)
{
    __shared__ float smem[16 * 67 + 16];   // 1088 floats; demod uses [0..511]
    int b = blockIdx.x;
    int t = threadIdx.x;

    if (b < 8) {
        // ---- demod: d[n][co] = rsqrt(RC_W^2 * sum_ci s^2 * wsq + 1e-8) ----
        const float RCW2 = 1.0f / 4608.0f;
        int n = b;
        for (int i = t; i < CIN_; i += 256) { float v = s[n * CIN_ + i]; smem[i] = v * v; }
        __syncthreads();
        for (int co = t; co < COUT_; co += 256) {
            float acc = 0.f;
            for (int ci = 0; ci < CIN_; ++ci)
                acc += smem[ci] * wsq[ci * COUT_ + co];
            dmod[n * COUT_ + co] = rsqrtf(RCW2 * acc + 1e-8f);
        }
    } else {
        int bb = b - 8;                  // n*32*66 + cb*66 + hp
        int hp = bb % 66;
        int cb = (bb / 66) % 32;
        int n  = bb / (66 * 32);
        int gh = hp - 1;
        bool rowok = (gh >= 0) && (gh < HH_);

        if (t < 16) smem[16 * 67 + t] = s[n * CIN_ + cb * 16 + t];
        if (rowok) {
            // 16 ci x 16 float4 = 256 threads, one float4 each (coalesced 256B/row)
            const float* src = &x[(((size_t)n * CIN_ + cb * 16) * HH_ + gh) * WW_];
            int ci = t >> 4;
            int g0 = (t & 15) * 4;
            float4 v = *(const float4*)&src[(size_t)ci * (HH_ * WW_) + g0];
            float* dstl = &smem[ci * 67 + g0];
            dstl[0] = v.x; dstl[1] = v.y; dstl[2] = v.z; dstl[3] = v.w;
        }
        __syncthreads();

        unsigned short* dst = xt + (((size_t)(n * 32 + cb) * 66 + hp) * 66) * 16;
        // 1056 u16 = 528 ushort2, coalesced
        for (int p = t; p < 528; p += 256) {
            int e  = p * 2;
            int wp = e >> 4;
            int ci = e & 15;
            int gw = wp - 1;
            float v0 = 0.f, v1 = 0.f;
            if (rowok && gw >= 0 && gw < WW_) {
                v0 = smem[ci * 67 + gw]       * smem[16 * 67 + ci];
                v1 = smem[(ci + 1) * 67 + gw] * smem[16 * 67 + ci + 1];
            }
            ushort2 o2; o2.x = f2bf(v0); o2.y = f2bf(v1);
            *(ushort2*)&dst[e] = o2;
        }
    }
}

// ============ main conv: implicit GEMM on 32x32x16 bf16 MFMA (round-3 exact math)
// block: M=128 spatial (8 rows x 16 cols patch), N=128 co; 4 waves, each 64x64.
// NEW: dispatch-index swizzle so the 4 cot-siblings (same x tile, different co)
// land on the SAME XCD (indices differ by 8) -> xt tile cached in one L2.
__global__ __launch_bounds__(256) void conv_mfma(
    const unsigned short* __restrict__ xt,
    const unsigned short* __restrict__ wb,
    const float* __restrict__ dmod,
    float* __restrict__ out)
{
    __shared__ __align__(16) union {
        struct { unsigned short xs[2880]; unsigned short ws[18432]; } s;  // 42624 B
        float o[64 * 129];                                                // 33024 B
    } sm;

    int disp = blockIdx.x;
    // disp = low3 + 8*sib + 32*ghi ; g = low3 | (ghi<<3) ; cot = sib
    int low3 = disp & 7;
    int cot  = (disp >> 3) & 3;
    int g    = low3 | ((disp >> 5) << 3);
    int wt_ = g & 3;
    int ht  = (g >> 2) & 7;
    int n   = g >> 5;
    int h0 = ht * 8, w0 = wt_ * 16, co0 = cot * 128;

    int t    = threadIdx.x;
    int wv   = t >> 6, lane = t & 63;
    int mh   = wv >> 1, nh = wv & 1;
    int l5   = lane & 31, half = lane >> 5;

    f32x16 acc[2][2];
#pragma unroll
    for (int ms = 0; ms < 2; ++ms)
#pragma unroll
        for (int ns = 0; ns < 2; ++ns)
#pragma unroll
            for (int i = 0; i < 16; ++i) acc[ms][ns][i] = 0.f;

    for (int cb = 0; cb < 32; ++cb) {
        // stage x halo tile: 10 rows x 18 wp x 16 ci (360 x 16B)
        const unsigned short* xb = xt + (((size_t)(n * 32 + cb) * 66 + h0) * 66 + w0) * 16;
        for (int li = t; li < 360; li += 256) {
            int row = li / 36;
            int off = li - row * 36;
            *(uint4*)&sm.s.xs[row * 288 + off * 8] = *(const uint4*)&xb[row * 1056 + off * 8];
        }
        // stage weights: 9 taps x 128 co x 16 ci (each tap = 256 x 16B)
        const unsigned short* wbb = wb + ((size_t)cb * 512 + co0) * 16;
#pragma unroll
        for (int tap = 0; tap < 9; ++tap) {
            *(uint4*)&sm.s.ws[tap * 2048 + t * 8] =
                *(const uint4*)&wbb[(size_t)tap * 32 * 512 * 16 + t * 8];
        }
        __syncthreads();

#pragma unroll
        for (int tap = 0; tap < 9; ++tap) {
            int kh = tap / 3, kw = tap - 3 * (tap / 3);
            bf16x8v bfr[2], afr[2];
#pragma unroll
            for (int ns = 0; ns < 2; ++ns) {
                int co_l = nh * 64 + ns * 32 + l5;
                bfr[ns] = *(const bf16x8v*)&sm.s.ws[tap * 2048 + co_l * 16 + half * 8];
            }
#pragma unroll
            for (int ms = 0; ms < 2; ++ms) {
                int pr = mh * 4 + ms * 2 + (l5 >> 4);
                int pc = l5 & 15;
                int pos = (pr + kh) * 18 + (pc + kw);
                afr[ms] = *(const bf16x8v*)&sm.s.xs[pos * 16 + half * 8];
            }
#pragma unroll
            for (int ms = 0; ms < 2; ++ms)
#pragma unroll
                for (int ns = 0; ns < 2; ++ns)
                    acc[ms][ns] = __builtin_amdgcn_mfma_f32_32x32x16_bf16(
                        afr[ms], bfr[ns], acc[ms][ns], 0, 0, 0);
        }
        __syncthreads();
    }

    // epilogue: demod + LDS transpose + coalesced float4 stores (2 passes)
    for (int p = 0; p < 2; ++p) {
        __syncthreads();
        int co_l = nh * 64 + p * 32 + l5;
        int bco  = nh * 32 + l5;
        float dv = dmod[n * COUT_ + co0 + co_l];
#pragma unroll
        for (int ms = 0; ms < 2; ++ms) {
#pragma unroll
            for (int reg = 0; reg < 16; ++reg) {
                int ml = (reg & 3) + 8 * (reg >> 2) + 4 * half;
                int pr = mh * 4 + ms * 2 + (ml >> 4);
                int pc = ml & 15;
                sm.o[bco * 129 + pr * 16 + pc] = acc[ms][p][reg] * dv;
            }
        }
        __syncthreads();
        for (int j = t; j < 2048; j += 256) {
            int wq = j & 3;
            int pairidx = j >> 2;
            int row  = pairidx & 7;
            int bco2 = pairidx >> 3;
            int co = (bco2 >> 5) * 64 + p * 32 + (bco2 & 31);
            const float* src = &sm.o[bco2 * 129 + row * 16 + wq * 4];
            float4 v = make_float4(src[0], src[1], src[2], src[3]);
            *(float4*)&out[(((size_t)n * COUT_ + co0 + co) * HH_ + h0 + row) * WW_ + w0 + wq * 4] = v;
        }
    }
}

extern "C" void kernel_launch(void* const* d_in, const int* in_sizes, int n_in,
                              void* d_out, int out_size, void* d_ws, size_t ws_size,
                              hipStream_t stream) {
    const float* x    = (const float*)d_in[0];
    const float* dlat = (const float*)d_in[1];
    const float* w    = (const float*)d_in[2];
    const float* mw   = (const float*)d_in[3];
    const float* mb   = (const float*)d_in[4];
    float* out = (float*)d_out;

    char* ws = (char*)d_ws;
    float* s    = (float*)(ws);                       // 4096 f
    float* dmod = (float*)(ws + 16384);               // 4096 f
    float* wsq  = (float*)(ws + 32768);               // 262144 f
    unsigned short* xt = (unsigned short*)(ws + 1081344);    // 17,842,176 u16
    unsigned short* wb = (unsigned short*)(ws + 36765696);   // 2,359,296 u16

    prep1<<<1320, 256, 0, stream>>>(w, dlat, mw, mb, wsq, wb, s);
    prep2<<<8 + NB_ * 32 * 66, 256, 0, stream>>>(x, s, wsq, dmod, xt);
    conv_mfma<<<1024, 256, 0, stream>>>(xt, wb, dmod, out);
}